// Round 6
// baseline (140.370 us; speedup 1.0000x reference)
//
#include <hip/hip_runtime.h>

namespace {

constexpr int BB = 64;
constexpr int DDIM = 196608;          // 3*256*256
constexpr float T_SCALE = 0.99f;      // 1 - 1/MAX_TIMESTEPS

// ws layout (floats). Per-block partials in bigp mirror ws offsets for idx<NRED.
constexpr int WS_ZD   = 0;            // 64*64  ZD[i][j] = z_i . d_j
constexpr int WS_DD   = 4096;         // 64*64  DD[i][j] = d_i . d_j
constexpr int WS_Z2   = 8192;         // 64     |z_i|^2
constexpr int WS_ELEM = 8256;         // 1      elementwise loss total
constexpr int NRED    = 8257;
constexpr int WS_U2   = 8320;         // 64 per-row sum(u^2)
constexpr int WS_BIGP = 8384;
constexpr int PSTRIDE = 8272;         // per-block stride (16B aligned)

__global__ void k_init(float* __restrict__ ws) {
  int idx = blockIdx.x * 256 + threadIdx.x;
  if (idx < NRED) ws[idx] = 0.0f;
}

// ---------------------------------------------------------------------------
// k_main: dual Grams + z2 + fused elementwise loss. 512 threads / 8 waves.
//   ZD[i][j] = z_i . d_j,  DD[i][j] = d_i . d_j,  z2[i] = |z_i|^2
//   elem = sum 0.5*(pm^2 + exp(plv)*plv) - pm*(d - z)
// GEMM: each wave computes one FULL 64x64 gram over a 16-wide k-slice:
//   waves 0-3 -> ZD (k-parts 0..3), waves 4-7 -> DD. 8x8 acc per lane.
// Staging: all 512 threads; thread t loads rows (t>>4) and (t>>4)+32 at
//   k-quad (t&15) for d,z (prefetched) + pm,plv (transient, elem only).
// LDS tiles k-major, quad XOR swizzle: word(k,r)=k*64+((r>>2)^(k&15))*4+(r&3);
//   b128 reads of row-octets are conflict-free broadcast8.
// OCCUPANCY PIN: amdgpu_waves_per_eu(4,4) caps the RA's occupancy target at
//   4 waves/EU -> 128-VGPR budget. __launch_bounds__(512,4) alone sets only
//   the MIN; the heuristic targeted 8 waves (64 VGPR) and spilled the 64-reg
//   accumulator (R4: VGPR=64, WRITE_SIZE=181MB of scratch traffic).
// ---------------------------------------------------------------------------
template <int SUBT, bool ATOMIC>
__global__
__attribute__((amdgpu_flat_work_group_size(512, 512), amdgpu_waves_per_eu(4, 4)))
void k_main(
    const float* __restrict__ data, const float* __restrict__ noise,
    const float* __restrict__ pmean, const float* __restrict__ plogv,
    float* __restrict__ ws, float* __restrict__ bigp) {
  __shared__ __align__(16) float dT[4096];
  __shared__ __align__(16) float zT[4096];
  __shared__ float esm[8];

  const int t = threadIdx.x;
  const int w = t >> 6;                // 0..7
  const int l = t & 63;
  const int li = l >> 3, lj = l & 7;   // 8x8 lane grid
  const int q = t & 15;                // staging k-quad
  const int rbase = t >> 4;            // staging row 0..31 (plus +32)
  const int part = w & 3;
  const int kbase = part << 4;
  const float* aT = (w < 4) ? zT : dT; // wave-uniform operand select
  const int chunk0 = blockIdx.x * (SUBT << 6);
  float* dst = ATOMIC ? ws : (bigp + (size_t)blockIdx.x * PSTRIDE);

  float acc[8][8];
#pragma unroll
  for (int a = 0; a < 8; ++a)
#pragma unroll
    for (int b = 0; b < 8; ++b) acc[a][b] = 0.0f;
  float z2p[2] = {0.f, 0.f};
  float eacc = 0.0f;
  float4 dv[2], zv[2];

  auto LOAD = [&](int s) {
#pragma unroll
    for (int it = 0; it < 2; ++it) {
      const int r = rbase + (it << 5);
      const size_t off = (size_t)r * DDIM + chunk0 + (s << 6) + (q << 2);
      dv[it] = *(const float4*)(data  + off);
      zv[it] = *(const float4*)(noise + off);
    }
  };
  auto WRITE = [&](int s) {
#pragma unroll
    for (int it = 0; it < 2; ++it) {
      const int r = rbase + (it << 5);
      const size_t off = (size_t)r * DDIM + chunk0 + (s << 6) + (q << 2);
      const float4 pm4 = *(const float4*)(pmean + off);
      const float4 pl4 = *(const float4*)(plogv + off);
      z2p[it] += zv[it].x * zv[it].x + zv[it].y * zv[it].y +
                 zv[it].z * zv[it].z + zv[it].w * zv[it].w;
      const float* dp = (const float*)&dv[it];
      const float* zp = (const float*)&zv[it];
      const float* pp = (const float*)&pm4;
      const float* gp = (const float*)&pl4;
#pragma unroll
      for (int e = 0; e < 4; ++e) {
        const float fc = dp[e] - zp[e];
        eacc += 0.5f * (pp[e] * pp[e] + __expf(gp[e]) * gp[e]) - pp[e] * fc;
      }
      const int rq = r >> 2, rm = r & 3;
#pragma unroll
      for (int e = 0; e < 4; ++e) {
        const int k = (q << 2) + e;
        const int word = (k << 6) + ((rq ^ (k & 15)) << 2) + rm;
        dT[word] = dp[e];
        zT[word] = zp[e];
      }
    }
  };

  LOAD(0);
  WRITE(0);
  for (int s = 0; s < SUBT; ++s) {
    if (s + 1 < SUBT) LOAD(s + 1);
    __syncthreads();                   // tile s writes visible
#pragma unroll 4
    for (int kk = 0; kk < 16; ++kk) {
      const int k   = kbase + kk;
      const int kb  = k << 6;
      const int sw2 = (k & 15) << 2;
      const float4 a0 = *(const float4*)(aT + kb + ((li << 3) ^ sw2));
      const float4 a1 = *(const float4*)(aT + kb + (((li << 3) | 4) ^ sw2));
      const float4 b0 = *(const float4*)(dT + kb + ((lj << 3) ^ sw2));
      const float4 b1 = *(const float4*)(dT + kb + (((lj << 3) | 4) ^ sw2));
      const float a8[8] = {a0.x, a0.y, a0.z, a0.w, a1.x, a1.y, a1.z, a1.w};
      const float b8[8] = {b0.x, b0.y, b0.z, b0.w, b1.x, b1.y, b1.z, b1.w};
#pragma unroll
      for (int ii = 0; ii < 8; ++ii)
#pragma unroll
        for (int jj = 0; jj < 8; ++jj)
          acc[ii][jj] = fmaf(a8[ii], b8[jj], acc[ii][jj]);
    }
    __syncthreads();                   // tile s reads done
    if (s + 1 < SUBT) WRITE(s + 1);
  }

  // ---- z2 / elem reductions (no LDS-tile interaction) ----
#pragma unroll
  for (int it = 0; it < 2; ++it) {
    float v = z2p[it];
    v += __shfl_xor(v, 1); v += __shfl_xor(v, 2);
    v += __shfl_xor(v, 4); v += __shfl_xor(v, 8);
    if ((l & 15) == 0) {
      const int r = rbase + (it << 5);
      if (ATOMIC) atomicAdd(ws + WS_Z2 + r, v);
      else        dst[WS_Z2 + r] = v;
    }
  }
  {
    float ev = eacc;
#pragma unroll
    for (int m = 1; m <= 32; m <<= 1) ev += __shfl_xor(ev, m);
    if (l == 0) esm[w] = ev;
  }

  // ---- 4-step k-part reduction into zT (ZD) / dT (DD) ----
  float* outT = (w < 4) ? zT : dT;
#pragma unroll
  for (int p = 0; p < 4; ++p) {
    if (part == p) {
#pragma unroll
      for (int ii = 0; ii < 8; ++ii)
#pragma unroll
        for (int h = 0; h < 2; ++h) {
          float* ptr = outT + (((li << 3) + ii) << 6) + (lj << 3) + (h << 2);
          float4 v;
          v.x = acc[ii][h * 4 + 0]; v.y = acc[ii][h * 4 + 1];
          v.z = acc[ii][h * 4 + 2]; v.w = acc[ii][h * 4 + 3];
          if (p != 0) {
            const float4 o = *(const float4*)ptr;
            v.x += o.x; v.y += o.y; v.z += o.z; v.w += o.w;
          }
          *(float4*)ptr = v;
        }
    }
    __syncthreads();
  }

  // ---- stream per-block partials ----
  if (ATOMIC) {
#pragma unroll
    for (int e = 0; e < 8; ++e) {
      atomicAdd(ws + WS_ZD + (t << 3) + e, zT[(t << 3) + e]);
      atomicAdd(ws + WS_DD + (t << 3) + e, dT[(t << 3) + e]);
    }
    if (t == 0) {
      float s0 = 0.f;
#pragma unroll
      for (int e = 0; e < 8; ++e) s0 += esm[e];
      atomicAdd(ws + WS_ELEM, s0);
    }
  } else {
#pragma unroll
    for (int e = 0; e < 2; ++e) {
      *(float4*)(dst + WS_ZD + (t << 3) + (e << 2)) =
          *(const float4*)(zT + (t << 3) + (e << 2));
      *(float4*)(dst + WS_DD + (t << 3) + (e << 2)) =
          *(const float4*)(dT + (t << 3) + (e << 2));
    }
    if (t == 0) {
      float s0 = 0.f;
#pragma unroll
      for (int e = 0; e < 8; ++e) s0 += esm[e];
      dst[WS_ELEM] = s0;
    }
  }
}

// Fold NB per-block partials into ws[0..NRED). 8-way atomic contention only.
__global__ void k_reduce(const float* __restrict__ bigp, float* __restrict__ ws,
                         int nb) {
  const int idx = blockIdx.x * 64 + threadIdx.x;
  if (idx >= NRED) return;
  const int per = nb >> 3;
  const size_t b0 = (size_t)blockIdx.y * per;
  float s = 0.f;
#pragma unroll 4
  for (int b = 0; b < per; ++b)
    s += bigp[(b0 + b) * PSTRIDE + idx];
  atomicAdd(ws + idx, s);
}

// ---------------------------------------------------------------------------
// k_small: per row i — reconstruct cross/d2/n2 from Grams, softmax, then
//   sum_k u^2 = (w^T DD w - 2 w.cross_i + n2_i) / (1 - t + eps)^2
//   cross_ij = (1-t) ZD[i][j] + t DD[i][j]
//   n2_i = (1-t)^2 z2_i + 2t(1-t) ZD[i][i] + t^2 DD[i][i]
// ---------------------------------------------------------------------------
__global__ void k_small(const float* __restrict__ times, float* __restrict__ ws) {
  const int i = blockIdx.x;
  const int j = threadIdx.x;
  const double tt = (double)(times[i] * T_SCALE);
  const double omt = 1.0 - tt;
  const double var = omt * omt + 1e-8;
  const double inv2v = 1.0 / (2.0 * var);
  const double zd = (double)ws[WS_ZD + (i << 6) + j];
  const double dd = (double)ws[WS_DD + (i << 6) + j];
  const double cross = omt * zd + tt * dd;
  const double d2j = (double)ws[WS_DD + j * 65];
  const double lg = (2.0 * tt * cross - tt * tt * d2j) * inv2v;
  double m = lg;
#pragma unroll
  for (int msk = 1; msk <= 32; msk <<= 1) m = fmax(m, __shfl_xor(m, msk));
  const double e = exp(lg - m);
  double S = e;
#pragma unroll
  for (int msk = 1; msk <= 32; msk <<= 1) S += __shfl_xor(S, msk);
  const double wgt = e / S;

  __shared__ double wsh[64];
  wsh[j] = wgt;
  __syncthreads();
  double inner = 0.0;
#pragma unroll 8
  for (int j2 = 0; j2 < 64; ++j2)
    inner += wsh[j2] * (double)ws[WS_DD + (j << 6) + j2];
  double s1 = wgt * inner;
  double s2 = wgt * cross;
#pragma unroll
  for (int msk = 1; msk <= 32; msk <<= 1) {
    s1 += __shfl_xor(s1, msk);
    s2 += __shfl_xor(s2, msk);
  }
  if (j == 0) {
    const double zdii = (double)ws[WS_ZD + i * 65];
    const double d2i  = (double)ws[WS_DD + i * 65];
    const double z2i  = (double)ws[WS_Z2 + i];
    const double n2   = omt * omt * z2i + 2.0 * tt * omt * zdii + tt * tt * d2i;
    const double den  = omt + 1e-8;
    ws[WS_U2 + i] = (float)((s1 - 2.0 * s2 + n2) / (den * den));
  }
}

__global__ void k_final(const float* __restrict__ ws, float* __restrict__ out) {
  const int t = threadIdx.x;
  double v = 0.5 * (double)ws[WS_U2 + t];
  if (t == 0) v += (double)ws[WS_ELEM];
#pragma unroll
  for (int m = 1; m <= 32; m <<= 1) v += __shfl_xor(v, m);
  if (t == 0) out[0] = (float)(v / (double)((size_t)BB * DDIM));
}

}  // namespace

extern "C" void kernel_launch(void* const* d_in, const int* in_sizes, int n_in,
                              void* d_out, int out_size, void* d_ws, size_t ws_size,
                              hipStream_t stream) {
  const float* data  = (const float*)d_in[0];
  const float* noise = (const float*)d_in[1];
  const float* times = (const float*)d_in[2];
  const float* pmean = (const float*)d_in[3];
  const float* plogv = (const float*)d_in[4];
  float* out = (float*)d_out;
  float* ws  = (float*)d_ws;
  float* bigp = ws + WS_BIGP;

  const bool fits512 =
      ws_size >= ((size_t)WS_BIGP + (size_t)512 * PSTRIDE) * sizeof(float);

  k_init<<<dim3(33), dim3(256), 0, stream>>>(ws);
  if (fits512) {
    k_main<6, false><<<dim3(512), dim3(512), 0, stream>>>(
        data, noise, pmean, plogv, ws, bigp);
    k_reduce<<<dim3(130, 8), dim3(64), 0, stream>>>(bigp, ws, 512);
  } else {
    k_main<6, true><<<dim3(512), dim3(512), 0, stream>>>(
        data, noise, pmean, plogv, ws, bigp);
  }
  k_small<<<dim3(64), dim3(64), 0, stream>>>(times, ws);
  k_final<<<dim3(1), dim3(64), 0, stream>>>(ws, out);
}

// Round 7
// 67.322 us; speedup vs baseline: 2.0851x; 2.0851x over previous
//
#include <hip/hip_runtime.h>
#include <cstdint>

namespace {

constexpr int BB = 64;
constexpr int DDIM = 196608;          // 3*256*256
constexpr float T_SCALE = 0.99f;      // 1 - 1/MAX_TIMESTEPS

// ws layout (floats). Per-block partials in bigp mirror ws offsets for idx<NRED.
constexpr int WS_ZD   = 0;            // 64*64  ZD[i][j] = z_i . d_j
constexpr int WS_DD   = 4096;         // 64*64  DD[i][j] = d_i . d_j
constexpr int WS_Z2   = 8192;         // 64     |z_i|^2
constexpr int WS_ELEM = 8256;         // 1      elementwise loss total
constexpr int NRED    = 8257;
constexpr int WS_U2   = 8320;         // 64 per-row sum(u^2)
constexpr int WS_BIGP = 8384;
constexpr int PSTRIDE = 8272;         // per-block stride (16B aligned)

using f32x4  = __attribute__((ext_vector_type(4))) float;
using bf16x8 = __attribute__((ext_vector_type(8))) __bf16;

__device__ inline f32x4 MFMA(bf16x8 a, bf16x8 b, f32x4 c) {
  return __builtin_amdgcn_mfma_f32_16x16x32_bf16(a, b, c, 0, 0, 0);
}

__global__ void k_init(float* __restrict__ ws) {
  int idx = blockIdx.x * 256 + threadIdx.x;
  if (idx < NRED) ws[idx] = 0.0f;
}

// ---------------------------------------------------------------------------
// k_main (MFMA): dual Grams via bf16 3-split + z2 + fused elementwise loss.
//   x = hi + mid + lo (bitwise-truncated bf16 parts, exact residuals).
//   ZD ~= zh*dh + zh*dm + zm*dh + zm*dm + zh*dl + zl*dh  (err ~2^-24|z||d|)
//   DD likewise with d-splits on both sides.
// 256 threads / 4 waves; wave wv owns output row-band [wv*16, wv*16+16).
// LDS: 6 bf16 tiles [64 rows][8 chunks of 8 k], chunk-XOR swizzle c^=(r&7):
//   MFMA frag read = b128 at row (lane&15)+band, chunk s2*4+(lane>>4) --
//   conflict-free (8 lanes/bank-quad = BW floor).
// Staging: thread t = row (t>>2), k-quad 16*(t&3); f32 d/z prefetched in regs
//   (32 VGPR), pm/plv transient in WRITE. Accumulators live in AGPRs (MFMA),
//   arch-VGPR demand ~90 -- finally inside any allocator budget.
// ---------------------------------------------------------------------------
template <int SUBT, bool ATOMIC>
__global__ __launch_bounds__(256) void k_main(
    const float* __restrict__ data, const float* __restrict__ noise,
    const float* __restrict__ pmean, const float* __restrict__ plogv,
    float* __restrict__ ws, float* __restrict__ bigp) {
  __shared__ __align__(16) short lds[6 * 4096];   // zh zm zl dh dm dl
  __shared__ float esm[4];

  const int t  = threadIdx.x;
  const int wv = t >> 6;
  const int l  = t & 63;
  const int m0 = wv << 4;              // wave's output row-band
  const int sr = t >> 2;               // staging row 0..63
  const int kq = (t & 3) << 4;         // staging k offset 0,16,32,48
  const int chunk0 = blockIdx.x * (SUBT << 6);
  float* dst = ATOMIC ? ws : (bigp + (size_t)blockIdx.x * PSTRIDE);

  f32x4 zdacc[4], ddacc[4];
#pragma unroll
  for (int b = 0; b < 4; ++b) { zdacc[b] = 0.0f; ddacc[b] = 0.0f; }
  float z2acc = 0.0f, eacc = 0.0f;
  float4 dv[4], zv[4];

  auto LOAD = [&](int s) {
    const size_t base = (size_t)sr * DDIM + chunk0 + (s << 6) + kq;
#pragma unroll
    for (int i = 0; i < 4; ++i) {
      dv[i] = *(const float4*)(data  + base + (i << 2));
      zv[i] = *(const float4*)(noise + base + (i << 2));
    }
  };

  // split 16 f32 (regs) into 3 bf16 tiles starting at tile index tbase
  auto SPLIT = [&](const float4* v, int tbase) {
    uint32_t hi[8], mi[8], lo[8];
#pragma unroll
    for (int p = 0; p < 8; ++p) {
      const float a = ((const float*)v)[2 * p];
      const float b = ((const float*)v)[2 * p + 1];
      const uint32_t ha = __float_as_uint(a) & 0xFFFF0000u;
      const uint32_t hb = __float_as_uint(b) & 0xFFFF0000u;
      hi[p] = (ha >> 16) | hb;
      const float ra = a - __uint_as_float(ha);
      const float rb = b - __uint_as_float(hb);
      const uint32_t ma = __float_as_uint(ra) & 0xFFFF0000u;
      const uint32_t mb = __float_as_uint(rb) & 0xFFFF0000u;
      mi[p] = (ma >> 16) | mb;
      const float sa = ra - __uint_as_float(ma);
      const float sb = rb - __uint_as_float(mb);
      lo[p] = (__float_as_uint(sa) >> 16) |
              (__float_as_uint(sb) & 0xFFFF0000u);
    }
    const int c0 = kq >> 3;
    const int sw = sr & 7;
    char* base = (char*)lds;
#pragma unroll
    for (int sp = 0; sp < 3; ++sp) {
      const uint32_t* pk = (sp == 0) ? hi : (sp == 1) ? mi : lo;
      uint4 w0 = {pk[0], pk[1], pk[2], pk[3]};
      uint4 w1 = {pk[4], pk[5], pk[6], pk[7]};
      *(uint4*)(base + (tbase + sp) * 8192 + sr * 128 + ((c0 ^ sw) << 4)) = w0;
      *(uint4*)(base + (tbase + sp) * 8192 + sr * 128 +
                (((c0 + 1) ^ sw) << 4)) = w1;
    }
  };

  auto WRITE = [&](int s) {
    const size_t base = (size_t)sr * DDIM + chunk0 + (s << 6) + kq;
    float4 pmv[4], plv[4];
#pragma unroll
    for (int i = 0; i < 4; ++i) {
      pmv[i] = *(const float4*)(pmean + base + (i << 2));
      plv[i] = *(const float4*)(plogv + base + (i << 2));
    }
    SPLIT(zv, 0);
    SPLIT(dv, 3);
#pragma unroll
    for (int p = 0; p < 16; ++p) {
      const float d  = ((const float*)dv)[p];
      const float z  = ((const float*)zv)[p];
      const float pm = ((const float*)pmv)[p];
      const float pl = ((const float*)plv)[p];
      const float fc = d - z;
      eacc += 0.5f * (pm * pm + __expf(pl) * pl) - pm * fc;
      z2acc += z * z;
    }
  };

  LOAD(0);
  WRITE(0);
  for (int s = 0; s < SUBT; ++s) {
    if (s + 1 < SUBT) LOAD(s + 1);
    __syncthreads();                   // tile s writes visible
#pragma unroll
    for (int s2 = 0; s2 < 2; ++s2) {   // two K=32 steps per 64-k subtile
      const int rA   = m0 + (l & 15);
      const int cA   = (s2 << 2) + (l >> 4);
      const int offA = rA * 128 + ((cA ^ (rA & 7)) << 4);
      bf16x8 az[3], ad[3];
#pragma unroll
      for (int sp = 0; sp < 3; ++sp) {
        az[sp] = *(const bf16x8*)((const char*)lds + sp * 8192 + offA);
        ad[sp] = *(const bf16x8*)((const char*)lds + (3 + sp) * 8192 + offA);
      }
#pragma unroll
      for (int b = 0; b < 4; ++b) {
        const int rB   = (b << 4) + (l & 15);
        const int offB = rB * 128 + ((cA ^ (rB & 7)) << 4);
        bf16x8 bd[3];
#pragma unroll
        for (int sp = 0; sp < 3; ++sp)
          bd[sp] = *(const bf16x8*)((const char*)lds + (3 + sp) * 8192 + offB);
        zdacc[b] = MFMA(az[0], bd[0], zdacc[b]);
        zdacc[b] = MFMA(az[0], bd[1], zdacc[b]);
        zdacc[b] = MFMA(az[1], bd[0], zdacc[b]);
        zdacc[b] = MFMA(az[1], bd[1], zdacc[b]);
        zdacc[b] = MFMA(az[0], bd[2], zdacc[b]);
        zdacc[b] = MFMA(az[2], bd[0], zdacc[b]);
        ddacc[b] = MFMA(ad[0], bd[0], ddacc[b]);
        ddacc[b] = MFMA(ad[0], bd[1], ddacc[b]);
        ddacc[b] = MFMA(ad[1], bd[0], ddacc[b]);
        ddacc[b] = MFMA(ad[1], bd[1], ddacc[b]);
        ddacc[b] = MFMA(ad[0], bd[2], ddacc[b]);
        ddacc[b] = MFMA(ad[2], bd[0], ddacc[b]);
      }
    }
    __syncthreads();                   // tile s reads done
    if (s + 1 < SUBT) WRITE(s + 1);
  }

  // ---- z2 (4 lanes per row) / elem reductions ----
  {
    float v = z2acc;
    v += __shfl_xor(v, 1);
    v += __shfl_xor(v, 2);
    if ((l & 3) == 0) {
      if (ATOMIC) atomicAdd(ws + WS_Z2 + sr, v);
      else        dst[WS_Z2 + sr] = v;
    }
  }
  {
    float ev = eacc;
#pragma unroll
    for (int m = 1; m <= 32; m <<= 1) ev += __shfl_xor(ev, m);
    if (l == 0) esm[wv] = ev;
  }
  __syncthreads();
  if (t == 0) {
    const float s0 = esm[0] + esm[1] + esm[2] + esm[3];
    if (ATOMIC) atomicAdd(ws + WS_ELEM, s0);
    else        dst[WS_ELEM] = s0;
  }

  // ---- gram stores: C/D layout col=lane&15, row=4*(lane>>4)+reg ----
#pragma unroll
  for (int b = 0; b < 4; ++b)
#pragma unroll
    for (int rg = 0; rg < 4; ++rg) {
      const int row = m0 + ((l >> 4) << 2) + rg;
      const int col = (b << 4) + (l & 15);
      if (ATOMIC) {
        atomicAdd(ws + WS_ZD + row * 64 + col, zdacc[b][rg]);
        atomicAdd(ws + WS_DD + row * 64 + col, ddacc[b][rg]);
      } else {
        dst[WS_ZD + row * 64 + col] = zdacc[b][rg];
        dst[WS_DD + row * 64 + col] = ddacc[b][rg];
      }
    }
}

// Fold NB per-block partials into ws[0..NRED). 8-way atomic contention only.
__global__ void k_reduce(const float* __restrict__ bigp, float* __restrict__ ws,
                         int nb) {
  const int idx = blockIdx.x * 64 + threadIdx.x;
  if (idx >= NRED) return;
  const int per = nb >> 3;
  const size_t b0 = (size_t)blockIdx.y * per;
  float s = 0.f;
#pragma unroll 4
  for (int b = 0; b < per; ++b)
    s += bigp[(b0 + b) * PSTRIDE + idx];
  atomicAdd(ws + idx, s);
}

// ---------------------------------------------------------------------------
// k_small: per row i — reconstruct cross/d2/n2 from Grams, softmax, then
//   sum_k u^2 = (w^T DD w - 2 w.cross_i + n2_i) / (1 - t + eps)^2
//   cross_ij = (1-t) ZD[i][j] + t DD[i][j]
//   n2_i = (1-t)^2 z2_i + 2t(1-t) ZD[i][i] + t^2 DD[i][i]
// ---------------------------------------------------------------------------
__global__ void k_small(const float* __restrict__ times, float* __restrict__ ws) {
  const int i = blockIdx.x;
  const int j = threadIdx.x;
  const double tt = (double)(times[i] * T_SCALE);
  const double omt = 1.0 - tt;
  const double var = omt * omt + 1e-8;
  const double inv2v = 1.0 / (2.0 * var);
  const double zd = (double)ws[WS_ZD + (i << 6) + j];
  const double dd = (double)ws[WS_DD + (i << 6) + j];
  const double cross = omt * zd + tt * dd;
  const double d2j = (double)ws[WS_DD + j * 65];
  const double lg = (2.0 * tt * cross - tt * tt * d2j) * inv2v;
  double m = lg;
#pragma unroll
  for (int msk = 1; msk <= 32; msk <<= 1) m = fmax(m, __shfl_xor(m, msk));
  const double e = exp(lg - m);
  double S = e;
#pragma unroll
  for (int msk = 1; msk <= 32; msk <<= 1) S += __shfl_xor(S, msk);
  const double wgt = e / S;

  __shared__ double wsh[64];
  wsh[j] = wgt;
  __syncthreads();
  double inner = 0.0;
#pragma unroll 8
  for (int j2 = 0; j2 < 64; ++j2)
    inner += wsh[j2] * (double)ws[WS_DD + (j << 6) + j2];
  double s1 = wgt * inner;
  double s2 = wgt * cross;
#pragma unroll
  for (int msk = 1; msk <= 32; msk <<= 1) {
    s1 += __shfl_xor(s1, msk);
    s2 += __shfl_xor(s2, msk);
  }
  if (j == 0) {
    const double zdii = (double)ws[WS_ZD + i * 65];
    const double d2i  = (double)ws[WS_DD + i * 65];
    const double z2i  = (double)ws[WS_Z2 + i];
    const double n2   = omt * omt * z2i + 2.0 * tt * omt * zdii + tt * tt * d2i;
    const double den  = omt + 1e-8;
    ws[WS_U2 + i] = (float)((s1 - 2.0 * s2 + n2) / (den * den));
  }
}

__global__ void k_final(const float* __restrict__ ws, float* __restrict__ out) {
  const int t = threadIdx.x;
  double v = 0.5 * (double)ws[WS_U2 + t];
  if (t == 0) v += (double)ws[WS_ELEM];
#pragma unroll
  for (int m = 1; m <= 32; m <<= 1) v += __shfl_xor(v, m);
  if (t == 0) out[0] = (float)(v / (double)((size_t)BB * DDIM));
}

}  // namespace

extern "C" void kernel_launch(void* const* d_in, const int* in_sizes, int n_in,
                              void* d_out, int out_size, void* d_ws, size_t ws_size,
                              hipStream_t stream) {
  const float* data  = (const float*)d_in[0];
  const float* noise = (const float*)d_in[1];
  const float* times = (const float*)d_in[2];
  const float* pmean = (const float*)d_in[3];
  const float* plogv = (const float*)d_in[4];
  float* out = (float*)d_out;
  float* ws  = (float*)d_ws;
  float* bigp = ws + WS_BIGP;

  auto fits = [&](long long nb) {
    return ws_size >= ((size_t)WS_BIGP + (size_t)nb * PSTRIDE) * sizeof(float);
  };

  k_init<<<dim3(33), dim3(256), 0, stream>>>(ws);
  if (fits(1024)) {
    k_main<3, false><<<dim3(1024), dim3(256), 0, stream>>>(
        data, noise, pmean, plogv, ws, bigp);
    k_reduce<<<dim3(130, 8), dim3(64), 0, stream>>>(bigp, ws, 1024);
  } else if (fits(512)) {
    k_main<6, false><<<dim3(512), dim3(256), 0, stream>>>(
        data, noise, pmean, plogv, ws, bigp);
    k_reduce<<<dim3(130, 8), dim3(64), 0, stream>>>(bigp, ws, 512);
  } else {
    k_main<6, true><<<dim3(512), dim3(256), 0, stream>>>(
        data, noise, pmean, plogv, ws, bigp);
  }
  k_small<<<dim3(64), dim3(64), 0, stream>>>(times, ws);
  k_final<<<dim3(1), dim3(64), 0, stream>>>(ws, out);
}

// Round 8
// 57.897 us; speedup vs baseline: 2.4245x; 1.1628x over previous
//
#include <hip/hip_runtime.h>
#include <cstdint>

namespace {

constexpr int BB = 64;
constexpr int DDIM = 196608;          // 3*256*256
constexpr float T_SCALE = 0.99f;      // 1 - 1/MAX_TIMESTEPS

// ws layout (floats). Per-block partials in bigp mirror ws offsets for idx<NRED.
constexpr int WS_ZD   = 0;            // 64*64  ZD[i][j] = z_i . d_j
constexpr int WS_DD   = 4096;         // 64*64  DD[i][j] = d_i . d_j
constexpr int WS_Z2   = 8192;         // 64     |z_i|^2
constexpr int WS_ELEM = 8256;         // 1      elementwise loss total
constexpr int NRED    = 8257;
constexpr int WS_U2   = 8320;         // 64 per-row sum(u^2)
constexpr int WS_BIGP = 8384;
constexpr int PSTRIDE = 8272;         // per-block stride (16B aligned)

using f32x4  = __attribute__((ext_vector_type(4))) float;
using bf16x8 = __attribute__((ext_vector_type(8))) __bf16;

__device__ inline f32x4 MFMA(bf16x8 a, bf16x8 b, f32x4 c) {
  return __builtin_amdgcn_mfma_f32_16x16x32_bf16(a, b, c, 0, 0, 0);
}

__global__ void k_init(float* __restrict__ ws) {
  int idx = blockIdx.x * 256 + threadIdx.x;
  if (idx < NRED) ws[idx] = 0.0f;
}

// ---------------------------------------------------------------------------
// k_main (MFMA, overlapped): dual Grams via exact bf16 3-split, z2, elem loss.
//   ZD = zh(dh+dm+dl) + zm(dh+dm) + zl*dh   (err ~2^-24 |z||d| per elem)
//   DD likewise with d-splits both sides.
// 512 threads / 8 waves: wave wv -> gram (wv>>2) [0=ZD,1=DD], row-band
//   (wv&3)*16. Per wave: 4 col-blocks x K=32 x 6 split-terms = 48 MFMA/subtile.
// Pipeline per subtile (the R6 fix): {MFMA(s) || SPLIT+elem(s+1)} in one
//   barrier phase (separate pipes overlap), then a short {ds_write(s+1),
//   LOAD(s+2)} phase. pm/plv prefetched one phase ahead with d/z.
// Staging: thread t = row (t>>3), chunk c0=(t&7) of 8 k-floats; one b128
//   LDS write per tile. Chunk-XOR swizzle c^(r&7): all LDS b128 traffic
//   2-way-or-better (R6 measured 0 conflicts with same layout).
// ---------------------------------------------------------------------------
template <int SUBT, bool ATOMIC>
__global__ __launch_bounds__(512) void k_main(
    const float* __restrict__ data, const float* __restrict__ noise,
    const float* __restrict__ pmean, const float* __restrict__ plogv,
    float* __restrict__ ws, float* __restrict__ bigp) {
  __shared__ __align__(16) short lds[6 * 4096];   // zh zm zl dh dm dl
  __shared__ float esm[8];

  const int t  = threadIdx.x;
  const int wv = t >> 6;
  const int l  = t & 63;
  const int g  = wv >> 2;              // 0: ZD, 1: DD
  const int m0 = (wv & 3) << 4;        // output row-band
  const int sr = t >> 3;               // staging row 0..63
  const int c0 = t & 7;                // staging chunk (8 floats)
  const int chunk0 = blockIdx.x * (SUBT << 6);
  float* dst = ATOMIC ? ws : (bigp + (size_t)blockIdx.x * PSTRIDE);

  f32x4 acc[4];
#pragma unroll
  for (int b = 0; b < 4; ++b) acc[b] = 0.0f;
  float z2acc = 0.0f, eacc = 0.0f;
  float4 dv[2], zv[2], pv[2], gv[2];   // in-flight staging regs
  uint4 sZ[3], sD[3];                  // split results awaiting ds_write

  auto LOAD = [&](int s) {
    const size_t base = (size_t)sr * DDIM + chunk0 + (s << 6) + (c0 << 3);
#pragma unroll
    for (int i = 0; i < 2; ++i) {
      dv[i] = *(const float4*)(data  + base + (i << 2));
      zv[i] = *(const float4*)(noise + base + (i << 2));
      pv[i] = *(const float4*)(pmean + base + (i << 2));
      gv[i] = *(const float4*)(plogv + base + (i << 2));
    }
  };

  auto SPLIT8 = [&](const float4* v, uint4& H, uint4& M, uint4& L) {
    uint32_t h[4], m[4], lo[4];
    const float* f = (const float*)v;
#pragma unroll
    for (int p = 0; p < 4; ++p) {
      const float a = f[2 * p], b = f[2 * p + 1];
      const uint32_t ha = __float_as_uint(a) & 0xFFFF0000u;
      const uint32_t hb = __float_as_uint(b) & 0xFFFF0000u;
      h[p] = (ha >> 16) | hb;
      const float ra = a - __uint_as_float(ha);
      const float rb = b - __uint_as_float(hb);
      const uint32_t ma = __float_as_uint(ra) & 0xFFFF0000u;
      const uint32_t mb = __float_as_uint(rb) & 0xFFFF0000u;
      m[p] = (ma >> 16) | mb;
      const float sa = ra - __uint_as_float(ma);
      const float sb = rb - __uint_as_float(mb);
      lo[p] = (__float_as_uint(sa) >> 16) | (__float_as_uint(sb) & 0xFFFF0000u);
    }
    H = uint4{h[0], h[1], h[2], h[3]};
    M = uint4{m[0], m[1], m[2], m[3]};
    L = uint4{lo[0], lo[1], lo[2], lo[3]};
  };

  // split + elem + z2 on the regs from the last LOAD (register-only; the
  // compiler interleaves this VALU work with the MFMA stream below)
  auto SPLITCALC = [&]() {
    const float* df = (const float*)dv;
    const float* zf = (const float*)zv;
    const float* pf = (const float*)pv;
    const float* gf = (const float*)gv;
#pragma unroll
    for (int p = 0; p < 8; ++p) {
      const float d = df[p], z = zf[p], pm = pf[p], pl = gf[p];
      const float fc = d - z;
      eacc += 0.5f * (pm * pm + __expf(pl) * pl) - pm * fc;
      z2acc += z * z;
    }
    SPLIT8(zv, sZ[0], sZ[1], sZ[2]);
    SPLIT8(dv, sD[0], sD[1], sD[2]);
  };

  auto DSW = [&]() {
    char* base = (char*)lds + sr * 128 + ((c0 ^ (sr & 7)) << 4);
#pragma unroll
    for (int sp = 0; sp < 3; ++sp) {
      *(uint4*)(base + sp * 8192)       = sZ[sp];
      *(uint4*)(base + (3 + sp) * 8192) = sD[sp];
    }
  };

  auto MMA = [&]() {
#pragma unroll
    for (int s2 = 0; s2 < 2; ++s2) {
      const int rA   = m0 + (l & 15);
      const int cA   = (s2 << 2) + (l >> 4);
      const int offA = rA * 128 + ((cA ^ (rA & 7)) << 4);
      bf16x8 af[3];
#pragma unroll
      for (int sp = 0; sp < 3; ++sp)
        af[sp] = *(const bf16x8*)((const char*)lds + (g * 3 + sp) * 8192 + offA);
#pragma unroll
      for (int b = 0; b < 4; ++b) {
        const int rB   = (b << 4) + (l & 15);
        const int offB = rB * 128 + ((cA ^ (rB & 7)) << 4);
        bf16x8 bd[3];
#pragma unroll
        for (int sp = 0; sp < 3; ++sp)
          bd[sp] = *(const bf16x8*)((const char*)lds + (3 + sp) * 8192 + offB);
        acc[b] = MFMA(af[0], bd[0], acc[b]);
        acc[b] = MFMA(af[0], bd[1], acc[b]);
        acc[b] = MFMA(af[1], bd[0], acc[b]);
        acc[b] = MFMA(af[1], bd[1], acc[b]);
        acc[b] = MFMA(af[0], bd[2], acc[b]);
        acc[b] = MFMA(af[2], bd[0], acc[b]);
      }
    }
  };

  // prologue: stage tile 0, issue loads for tile 1
  LOAD(0);
  SPLITCALC();
  DSW();
  LOAD(1);
  __syncthreads();                     // tile 0 visible

  for (int s = 0; s < SUBT; ++s) {
    if (s + 1 < SUBT) SPLITCALC();     // VALU stream (tile s+1)
    MMA();                             // MFMA stream (tile s) — co-issued
    __syncthreads();                   // tile s reads done
    if (s + 1 < SUBT) {
      DSW();                           // commit tile s+1
      if (s + 2 < SUBT) LOAD(s + 2);   // issue next loads
      __syncthreads();                 // tile s+1 visible
    }
  }

  // ---- z2 (8 staging lanes per row) / elem reductions ----
  {
    float v = z2acc;
    v += __shfl_xor(v, 1);
    v += __shfl_xor(v, 2);
    v += __shfl_xor(v, 4);
    if ((l & 7) == 0) {
      if (ATOMIC) atomicAdd(ws + WS_Z2 + sr, v);
      else        dst[WS_Z2 + sr] = v;
    }
  }
  {
    float ev = eacc;
#pragma unroll
    for (int m = 1; m <= 32; m <<= 1) ev += __shfl_xor(ev, m);
    if (l == 0) esm[wv] = ev;
  }
  __syncthreads();
  if (t == 0) {
    float s0 = 0.f;
#pragma unroll
    for (int e = 0; e < 8; ++e) s0 += esm[e];
    if (ATOMIC) atomicAdd(ws + WS_ELEM, s0);
    else        dst[WS_ELEM] = s0;
  }

  // ---- gram stores: C/D layout col=lane&15, row=4*(lane>>4)+reg ----
  const int grOff = (g == 0) ? WS_ZD : WS_DD;
#pragma unroll
  for (int b = 0; b < 4; ++b)
#pragma unroll
    for (int rg = 0; rg < 4; ++rg) {
      const int row = m0 + ((l >> 4) << 2) + rg;
      const int col = (b << 4) + (l & 15);
      if (ATOMIC) atomicAdd(ws + grOff + row * 64 + col, acc[b][rg]);
      else        dst[grOff + row * 64 + col] = acc[b][rg];
    }
}

// Fold NB per-block partials into ws[0..NRED). 8-way atomic contention only.
__global__ void k_reduce(const float* __restrict__ bigp, float* __restrict__ ws,
                         int nb) {
  const int idx = blockIdx.x * 64 + threadIdx.x;
  if (idx >= NRED) return;
  const int per = nb >> 3;
  const size_t b0 = (size_t)blockIdx.y * per;
  float s = 0.f;
#pragma unroll 4
  for (int b = 0; b < per; ++b)
    s += bigp[(b0 + b) * PSTRIDE + idx];
  atomicAdd(ws + idx, s);
}

// ---------------------------------------------------------------------------
// k_small: per row i — reconstruct cross/d2/n2 from Grams, softmax, then
//   sum_k u^2 = (w^T DD w - 2 w.cross_i + n2_i) / (1 - t + eps)^2
//   cross_ij = (1-t) ZD[i][j] + t DD[i][j]
//   n2_i = (1-t)^2 z2_i + 2t(1-t) ZD[i][i] + t^2 DD[i][i]
// ---------------------------------------------------------------------------
__global__ void k_small(const float* __restrict__ times, float* __restrict__ ws) {
  const int i = blockIdx.x;
  const int j = threadIdx.x;
  const double tt = (double)(times[i] * T_SCALE);
  const double omt = 1.0 - tt;
  const double var = omt * omt + 1e-8;
  const double inv2v = 1.0 / (2.0 * var);
  const double zd = (double)ws[WS_ZD + (i << 6) + j];
  const double dd = (double)ws[WS_DD + (i << 6) + j];
  const double cross = omt * zd + tt * dd;
  const double d2j = (double)ws[WS_DD + j * 65];
  const double lg = (2.0 * tt * cross - tt * tt * d2j) * inv2v;
  double m = lg;
#pragma unroll
  for (int msk = 1; msk <= 32; msk <<= 1) m = fmax(m, __shfl_xor(m, msk));
  const double e = exp(lg - m);
  double S = e;
#pragma unroll
  for (int msk = 1; msk <= 32; msk <<= 1) S += __shfl_xor(S, msk);
  const double wgt = e / S;

  __shared__ double wsh[64];
  wsh[j] = wgt;
  __syncthreads();
  double inner = 0.0;
#pragma unroll 8
  for (int j2 = 0; j2 < 64; ++j2)
    inner += wsh[j2] * (double)ws[WS_DD + (j << 6) + j2];
  double s1 = wgt * inner;
  double s2 = wgt * cross;
#pragma unroll
  for (int msk = 1; msk <= 32; msk <<= 1) {
    s1 += __shfl_xor(s1, msk);
    s2 += __shfl_xor(s2, msk);
  }
  if (j == 0) {
    const double zdii = (double)ws[WS_ZD + i * 65];
    const double d2i  = (double)ws[WS_DD + i * 65];
    const double z2i  = (double)ws[WS_Z2 + i];
    const double n2   = omt * omt * z2i + 2.0 * tt * omt * zdii + tt * tt * d2i;
    const double den  = omt + 1e-8;
    ws[WS_U2 + i] = (float)((s1 - 2.0 * s2 + n2) / (den * den));
  }
}

__global__ void k_final(const float* __restrict__ ws, float* __restrict__ out) {
  const int t = threadIdx.x;
  double v = 0.5 * (double)ws[WS_U2 + t];
  if (t == 0) v += (double)ws[WS_ELEM];
#pragma unroll
  for (int m = 1; m <= 32; m <<= 1) v += __shfl_xor(v, m);
  if (t == 0) out[0] = (float)(v / (double)((size_t)BB * DDIM));
}

}  // namespace

extern "C" void kernel_launch(void* const* d_in, const int* in_sizes, int n_in,
                              void* d_out, int out_size, void* d_ws, size_t ws_size,
                              hipStream_t stream) {
  const float* data  = (const float*)d_in[0];
  const float* noise = (const float*)d_in[1];
  const float* times = (const float*)d_in[2];
  const float* pmean = (const float*)d_in[3];
  const float* plogv = (const float*)d_in[4];
  float* out = (float*)d_out;
  float* ws  = (float*)d_ws;
  float* bigp = ws + WS_BIGP;

  const bool fits512 =
      ws_size >= ((size_t)WS_BIGP + (size_t)512 * PSTRIDE) * sizeof(float);

  k_init<<<dim3(33), dim3(256), 0, stream>>>(ws);
  if (fits512) {
    k_main<6, false><<<dim3(512), dim3(512), 0, stream>>>(
        data, noise, pmean, plogv, ws, bigp);
    k_reduce<<<dim3(130, 8), dim3(64), 0, stream>>>(bigp, ws, 512);
  } else {
    k_main<6, true><<<dim3(512), dim3(512), 0, stream>>>(
        data, noise, pmean, plogv, ws, bigp);
  }
  k_small<<<dim3(64), dim3(64), 0, stream>>>(times, ws);
  k_final<<<dim3(1), dim3(64), 0, stream>>>(ws, out);
}